// Round 8
// baseline (41371.204 us; speedup 1.0000x reference)
//
#include <hip/hip_runtime.h>
#include <stdint.h>

#define MDIM   1024
#define NGATE5 5120
#define TSTEPS 8192
#define NWG    128
#define NTHR   512
#define SSTR   64     // u64 units between slot-PAIRS (512 B): spread across LLC channels

typedef unsigned int u32x4 __attribute__((ext_vector_type(4)));

__device__ __forceinline__ float sigmoidf_(float x) {
  return 1.f / (1.f + __expf(-x));
}
// Fast tanh: avoids OCML tanhf on the critical path. ~1e-6 abs err.
__device__ __forceinline__ float tanhf_(float x) {
  float ax = fminf(fabsf(x), 15.f);
  float e = __expf(2.f * ax);
  float t = 1.f - 2.f / (e + 1.f);
  return copysignf(t, x);
}

// One 16-B LLC-coherent load (bypasses L1/L2: per-XCD L2s are not coherent).
// (R5: acquire-fence invalidate storms = 3.8x worse. R7: 8x replication =
// producer store-merge storms, worse. Bypass polls on a SPREAD address set
// is this round's variable.)
__device__ __forceinline__ u32x4 load16_coherent(const unsigned long long* p) {
  u32x4 r;
  asm volatile("global_load_dwordx4 %0, %1, off sc0 sc1\n\t"
               "s_waitcnt vmcnt(0)"
               : "=&v"(r) : "v"(p) : "memory");
  return r;
}

__device__ __forceinline__ unsigned long long pack_slot(float v, unsigned tag) {
  return ((unsigned long long)tag << 32) | (unsigned long long)__float_as_uint(v);
}

// Slot addressing: pair p (columns 2p,2p+1) lives at base + p*SSTR (+0/+1).
__device__ __forceinline__ unsigned long long* slot_addr(unsigned long long* base, int j) {
  return base + (size_t)(j >> 1) * SSTR + (j & 1);
}

// ---------------------------------------------------------------------------
// Prepass: xproj[t][r] = inputs[t,:]@Wx[r,:] + bx[r] + (r<4M ? bh[r] : bm[r-4M])
// ---------------------------------------------------------------------------
#define GT_K 16
__global__ __launch_bounds__(256) void xproj_gemm(
    const float* __restrict__ A, const float* __restrict__ W,
    const float* __restrict__ bx, const float* __restrict__ bh,
    const float* __restrict__ bm, float* __restrict__ C)
{
  __shared__ float As[GT_K][64 + 4];
  __shared__ float Ws[GT_K][64 + 4];
  const int tid = threadIdx.x;
  const int tx = tid & 15, ty = tid >> 4;
  const int m0 = blockIdx.x * 64;
  const int n0 = blockIdx.y * 64;
  const int lr = tid >> 2;
  const int lk = (tid & 3) * 4;

  float acc[4][4] = {};
  for (int kb = 0; kb < MDIM; kb += GT_K) {
    const float4 av = *(const float4*)(A + (size_t)(m0 + lr) * MDIM + kb + lk);
    const float4 wv = *(const float4*)(W + (size_t)(n0 + lr) * MDIM + kb + lk);
    __syncthreads();
    As[lk + 0][lr] = av.x; As[lk + 1][lr] = av.y;
    As[lk + 2][lr] = av.z; As[lk + 3][lr] = av.w;
    Ws[lk + 0][lr] = wv.x; Ws[lk + 1][lr] = wv.y;
    Ws[lk + 2][lr] = wv.z; Ws[lk + 3][lr] = wv.w;
    __syncthreads();
    #pragma unroll
    for (int kk = 0; kk < GT_K; ++kk) {
      const float4 a = *(const float4*)(&As[kk][ty * 4]);
      const float4 w = *(const float4*)(&Ws[kk][tx * 4]);
      acc[0][0] += a.x * w.x; acc[0][1] += a.x * w.y; acc[0][2] += a.x * w.z; acc[0][3] += a.x * w.w;
      acc[1][0] += a.y * w.x; acc[1][1] += a.y * w.y; acc[1][2] += a.y * w.z; acc[1][3] += a.y * w.w;
      acc[2][0] += a.z * w.x; acc[2][1] += a.z * w.y; acc[2][2] += a.z * w.z; acc[2][3] += a.z * w.w;
      acc[3][0] += a.w * w.x; acc[3][1] += a.w * w.y; acc[3][2] += a.w * w.z; acc[3][3] += a.w * w.w;
    }
  }
  const int rbase = n0 + tx * 4;
  float bias[4];
  #pragma unroll
  for (int q = 0; q < 4; ++q) {
    const int r = rbase + q;
    bias[q] = bx[r] + (r < 4 * MDIM ? bh[r] : bm[r - 4 * MDIM]);
  }
  #pragma unroll
  for (int i = 0; i < 4; ++i) {
    const int row = m0 + ty * 4 + i;
    float4 o;
    o.x = acc[i][0] + bias[0]; o.y = acc[i][1] + bias[1];
    o.z = acc[i][2] + bias[2]; o.w = acc[i][3] + bias[3];
    *(float4*)(C + (size_t)row * NGATE5 + rbase) = o;
  }
}

// ---------------------------------------------------------------------------
// Recurrence: 128 WGs x 512 threads (8 waves). Wave w owns column j=wg*8+w.
// Wh fp32 in LDS (128 KB), Wm in 16 VGPRs/lane. Slots strided 512 B/pair.
// Critical path: h -> z-dot -> publish v -> (i,o,f dots overlap v-wait) ->
// v -> u-dot -> c,h -> publish h.
// ---------------------------------------------------------------------------
__global__ __launch_bounds__(NTHR, 2) void ulstm_persistent_p(
    const float* __restrict__ Wh, const float* __restrict__ Wm,
    const float* __restrict__ xproj, float* __restrict__ out,
    unsigned long long* __restrict__ hbase, unsigned long long* __restrict__ vbase)
{
  __shared__ alignas(16) float sWh[32][MDIM];   // [wave*4+gate][k]  128 KB
  __shared__ alignas(16) float hbuf[MDIM];
  __shared__ alignas(16) float vbuf[MDIM];

  const int tid  = threadIdx.x;
  const int wg   = blockIdx.x;
  const int wave = tid >> 6;
  const int lane = tid & 63;
  const int j    = wg * 8 + wave;          // owned column, 0..1023
  const int sb   = tid * 2;                // this thread stages columns sb, sb+1
  const unsigned long long* hpair = hbase + (size_t)tid * SSTR;
  const unsigned long long* vpair = vbase + (size_t)tid * SSTR;

  // ---- one-time weight staging: Wh -> LDS (fp32, float4) ----
  for (int idx = tid; idx < 32 * 256; idx += NTHR) {
    const int r = idx >> 8, k4 = (idx & 255) * 4;
    const int w_ = r >> 2, g = r & 3;
    *(float4*)(&sWh[r][k4]) =
        *(const float4*)(Wh + (size_t)(g * MDIM + wg * 8 + w_) * MDIM + k4);
  }
  // ---- Wm row for owned column -> registers (16 floats/lane) ----
  float wm[16];
  #pragma unroll
  for (int i = 0; i < 4; ++i) {
    const float4 v = *(const float4*)(Wm + (size_t)j * MDIM + i * 256 + lane * 4);
    wm[i * 4 + 0] = v.x; wm[i * 4 + 1] = v.y;
    wm[i * 4 + 2] = v.z; wm[i * 4 + 3] = v.w;
  }
  __syncthreads();

  float c = 0.f, hlast = 0.f, tc = 0.f;   // tc = tanh(c), maintained off-path

  for (int t = 0; t < TSTEPS; ++t) {
    // xproj for this step (issued before the poll; first poll round drains it)
    const float* xp = xproj + (size_t)t * NGATE5 + j;
    const float xw0 = xp[0 * MDIM];
    const float xw1 = xp[1 * MDIM];
    const float xw2 = xp[2 * MDIM];
    const float xw3 = xp[3 * MDIM];
    const float xw4 = xp[4 * MDIM];

    // ---- wait for h(t-1): tag==t (memset gives tag0/val0 = h(-1)=0) ----
    {
      u32x4 a;
      for (;;) {
        a = load16_coherent(hpair);
        if (a.y == (unsigned)t && a.w == (unsigned)t) break;
      }
      hbuf[sb + 0] = __uint_as_float(a.x);
      hbuf[sb + 1] = __uint_as_float(a.z);
    }
    __syncthreads();  // S2

    // ---- z-dot only (critical path), then publish v ----
    float hd2 = 0.f;
    #pragma unroll
    for (int i = 0; i < 4; ++i) {
      const int kb = i * 256 + lane * 4;
      const float4 hv = *(const float4*)(hbuf + kb);
      const float4 w2 = *(const float4*)(&sWh[wave * 4 + 2][kb]);
      hd2 += w2.x * hv.x + w2.y * hv.y + w2.z * hv.z + w2.w * hv.w;
    }
    #pragma unroll
    for (int off = 32; off > 0; off >>= 1) hd2 += __shfl_xor(hd2, off, 64);

    const float zg = sigmoidf_(xw2 + hd2);
    const float vj = zg * tc;
    if (lane == 0) {
      __hip_atomic_store(slot_addr(vbase, j), pack_slot(vj, (unsigned)(t + 1)),
                         __ATOMIC_RELAXED, __HIP_MEMORY_SCOPE_AGENT);
    }

    // ---- i,o,f dots: overlap with the v-exchange ----
    float hd0 = 0.f, hd1 = 0.f, hd3 = 0.f;
    #pragma unroll
    for (int i = 0; i < 4; ++i) {
      const int kb = i * 256 + lane * 4;
      const float4 hv = *(const float4*)(hbuf + kb);
      const float4 w0 = *(const float4*)(&sWh[wave * 4 + 0][kb]);
      const float4 w1 = *(const float4*)(&sWh[wave * 4 + 1][kb]);
      const float4 w3 = *(const float4*)(&sWh[wave * 4 + 3][kb]);
      hd0 += w0.x * hv.x + w0.y * hv.y + w0.z * hv.z + w0.w * hv.w;
      hd1 += w1.x * hv.x + w1.y * hv.y + w1.z * hv.z + w1.w * hv.w;
      hd3 += w3.x * hv.x + w3.y * hv.y + w3.z * hv.z + w3.w * hv.w;
    }
    #pragma unroll
    for (int off = 32; off > 0; off >>= 1) {
      hd0 += __shfl_xor(hd0, off, 64);
      hd1 += __shfl_xor(hd1, off, 64);
      hd3 += __shfl_xor(hd3, off, 64);
    }
    const float ig = sigmoidf_(xw0 + hd0);
    const float og = sigmoidf_(xw1 + hd1);
    const float fg = sigmoidf_(xw3 + hd3);

    // ---- wait for v(t): tag==t+1 ----
    {
      u32x4 a;
      for (;;) {
        a = load16_coherent(vpair);
        if (a.y == (unsigned)(t + 1) && a.w == (unsigned)(t + 1)) break;
      }
      vbuf[sb + 0] = __uint_as_float(a.x);
      vbuf[sb + 1] = __uint_as_float(a.z);
    }
    __syncthreads();  // S3

    // ---- u-dot from registers ----
    float md = 0.f;
    #pragma unroll
    for (int i = 0; i < 4; ++i) {
      const int kb = i * 256 + lane * 4;
      const float4 vv = *(const float4*)(vbuf + kb);
      md += wm[i*4+0]*vv.x + wm[i*4+1]*vv.y + wm[i*4+2]*vv.z + wm[i*4+3]*vv.w;
    }
    #pragma unroll
    for (int off = 32; off > 0; off >>= 1) md += __shfl_xor(md, off, 64);

    const float u = tanhf_(xw4 + md);
    c = ig * u + fg * c;
    const float tcn = tanhf_(c);
    hlast = og * tcn;
    if (lane == 0) {
      __hip_atomic_store(slot_addr(hbase, j), pack_slot(hlast, (unsigned)(t + 1)),
                         __ATOMIC_RELAXED, __HIP_MEMORY_SCOPE_AGENT);
    }
    tc = tcn;
  }

  if (lane == 0) {
    out[j] = c;
    out[MDIM + j] = hlast;
  }
}

// ---------------------------------------------------------------------------
// Fallback (ws too small for xproj): 256 WGs x 256 thr, strided slots,
// 2 pair-loads fused per poll round.
// ---------------------------------------------------------------------------
__global__ __launch_bounds__(256, 1) void ulstm_persistent_f(
    const float* __restrict__ inputs, const float* __restrict__ Wx,
    const float* __restrict__ bx, const float* __restrict__ Wh,
    const float* __restrict__ bh, const float* __restrict__ Wm,
    const float* __restrict__ bm, float* __restrict__ out,
    unsigned long long* __restrict__ hbase, unsigned long long* __restrict__ vbase)
{
  __shared__ alignas(16) float xbuf[MDIM];
  __shared__ alignas(16) float hbuf[MDIM];
  __shared__ alignas(16) float vbuf[MDIM];

  const int tid  = threadIdx.x;
  const int wg   = blockIdx.x;
  const int wave = tid >> 6;
  const int lane = tid & 63;
  const int j    = wg * 4 + wave;
  const int sb   = tid * 4;   // stages columns sb..sb+3 (pairs 2tid, 2tid+1)

  const float bxi = bx[j],            bxo = bx[MDIM + j],
              bxz = bx[2 * MDIM + j], bxf = bx[3 * MDIM + j],
              bxu = bx[4 * MDIM + j];
  const float bhi = bh[j],            bho = bh[MDIM + j],
              bhz = bh[2 * MDIM + j], bhf = bh[3 * MDIM + j];
  const float bmj = bm[j];

  float c = 0.f, hlast = 0.f;

  for (int t = 0; t < TSTEPS; ++t) {
    {
      float4 v = ((const float4*)(inputs + (size_t)t * MDIM))[tid];
      ((float4*)xbuf)[tid] = v;
    }
    __syncthreads();

    float xd[5] = {0, 0, 0, 0, 0};
    #pragma unroll
    for (int i = 0; i < 4; ++i) {
      const int kb = i * 256 + lane * 4;
      const float4 xv = *(const float4*)(xbuf + kb);
      #pragma unroll
      for (int g = 0; g < 5; ++g) {
        const float4 w = *(const float4*)(Wx + ((size_t)(g * MDIM + j)) * MDIM + kb);
        xd[g] += w.x * xv.x + w.y * xv.y + w.z * xv.z + w.w * xv.w;
      }
    }
    #pragma unroll
    for (int off = 32; off > 0; off >>= 1)
      #pragma unroll
      for (int g = 0; g < 5; ++g) xd[g] += __shfl_xor(xd[g], off, 64);

    {
      u32x4 a, b;
      const unsigned long long* p0 = hbase + (size_t)(2 * tid) * SSTR;
      const unsigned long long* p1 = hbase + (size_t)(2 * tid + 1) * SSTR;
      for (;;) {
        asm volatile("global_load_dwordx4 %0, %2, off sc0 sc1\n\t"
                     "global_load_dwordx4 %1, %3, off sc0 sc1\n\t"
                     "s_waitcnt vmcnt(0)"
                     : "=&v"(a), "=&v"(b) : "v"(p0), "v"(p1) : "memory");
        if (a.y == (unsigned)t && a.w == (unsigned)t &&
            b.y == (unsigned)t && b.w == (unsigned)t) break;
      }
      hbuf[sb + 0] = __uint_as_float(a.x);
      hbuf[sb + 1] = __uint_as_float(a.z);
      hbuf[sb + 2] = __uint_as_float(b.x);
      hbuf[sb + 3] = __uint_as_float(b.z);
    }
    __syncthreads();

    float hd[4] = {0, 0, 0, 0};
    #pragma unroll
    for (int i = 0; i < 4; ++i) {
      const int kb = i * 256 + lane * 4;
      const float4 hv = *(const float4*)(hbuf + kb);
      #pragma unroll
      for (int g = 0; g < 4; ++g) {
        const float4 w = *(const float4*)(Wh + ((size_t)(g * MDIM + j)) * MDIM + kb);
        hd[g] += w.x * hv.x + w.y * hv.y + w.z * hv.z + w.w * hv.w;
      }
    }
    #pragma unroll
    for (int off = 32; off > 0; off >>= 1)
      #pragma unroll
      for (int g = 0; g < 4; ++g) hd[g] += __shfl_xor(hd[g], off, 64);

    const float ig = sigmoidf_(xd[0] + bxi + hd[0] + bhi);
    const float og = sigmoidf_(xd[1] + bxo + hd[1] + bho);
    const float zg = sigmoidf_(xd[2] + bxz + hd[2] + bhz);
    const float fg = sigmoidf_(xd[3] + bxf + hd[3] + bhf);
    const float vj = zg * tanhf_(c);
    if (lane == 0)
      __hip_atomic_store(slot_addr(vbase, j), pack_slot(vj, (unsigned)(t + 1)),
                         __ATOMIC_RELAXED, __HIP_MEMORY_SCOPE_AGENT);

    {
      u32x4 a, b;
      const unsigned long long* p0 = vbase + (size_t)(2 * tid) * SSTR;
      const unsigned long long* p1 = vbase + (size_t)(2 * tid + 1) * SSTR;
      for (;;) {
        asm volatile("global_load_dwordx4 %0, %2, off sc0 sc1\n\t"
                     "global_load_dwordx4 %1, %3, off sc0 sc1\n\t"
                     "s_waitcnt vmcnt(0)"
                     : "=&v"(a), "=&v"(b) : "v"(p0), "v"(p1) : "memory");
        if (a.y == (unsigned)(t + 1) && a.w == (unsigned)(t + 1) &&
            b.y == (unsigned)(t + 1) && b.w == (unsigned)(t + 1)) break;
      }
      vbuf[sb + 0] = __uint_as_float(a.x);
      vbuf[sb + 1] = __uint_as_float(a.z);
      vbuf[sb + 2] = __uint_as_float(b.x);
      vbuf[sb + 3] = __uint_as_float(b.z);
    }
    __syncthreads();

    float md = 0;
    #pragma unroll
    for (int i = 0; i < 4; ++i) {
      const int kb = i * 256 + lane * 4;
      const float4 vv = *(const float4*)(vbuf + kb);
      const float4 w = *(const float4*)(Wm + (size_t)j * MDIM + kb);
      md += w.x * vv.x + w.y * vv.y + w.z * vv.z + w.w * vv.w;
    }
    #pragma unroll
    for (int off = 32; off > 0; off >>= 1) md += __shfl_xor(md, off, 64);

    const float u = tanhf_(xd[4] + bxu + md + bmj);
    c = ig * u + fg * c;
    hlast = og * tanhf_(c);
    if (lane == 0)
      __hip_atomic_store(slot_addr(hbase, j), pack_slot(hlast, (unsigned)(t + 1)),
                         __ATOMIC_RELAXED, __HIP_MEMORY_SCOPE_AGENT);
  }

  if (lane == 0) {
    out[j] = c;
    out[MDIM + j] = hlast;
  }
}

extern "C" void kernel_launch(void* const* d_in, const int* in_sizes, int n_in,
                              void* d_out, int out_size, void* d_ws, size_t ws_size,
                              hipStream_t stream) {
  const float* inputs = (const float*)d_in[0];
  const float* Wx     = (const float*)d_in[1];
  const float* bx     = (const float*)d_in[2];
  const float* Wh     = (const float*)d_in[3];
  const float* bh     = (const float*)d_in[4];
  const float* Wm     = (const float*)d_in[5];
  const float* bm     = (const float*)d_in[6];
  float* out = (float*)d_out;

  // 512 pairs x 512 B per array
  const size_t arr_u64 = (size_t)(MDIM / 2) * SSTR;
  unsigned long long* hbase = (unsigned long long*)d_ws;
  unsigned long long* vbase = hbase + arr_u64;
  const size_t slot_bytes = 2 * arr_u64 * sizeof(unsigned long long);  // 512 KB
  const size_t xp_bytes   = (size_t)TSTEPS * NGATE5 * sizeof(float);

  // tag 0 / value 0.0f == initial h state
  hipMemsetAsync(d_ws, 0, slot_bytes, stream);

  if (ws_size >= slot_bytes + xp_bytes) {
    float* xproj = (float*)((char*)d_ws + slot_bytes);
    xproj_gemm<<<dim3(TSTEPS / 64, NGATE5 / 64), 256, 0, stream>>>(
        inputs, Wx, bx, bh, bm, xproj);
    ulstm_persistent_p<<<NWG, NTHR, 0, stream>>>(Wh, Wm, xproj, out, hbase, vbase);
  } else {
    ulstm_persistent_f<<<256, 256, 0, stream>>>(inputs, Wx, bx, Wh, bh, Wm, bm,
                                                out, hbase, vbase);
  }
}

// Round 9
// 40015.765 us; speedup vs baseline: 1.0339x; 1.0339x over previous
//
#include <hip/hip_runtime.h>
#include <stdint.h>

#define MDIM   1024
#define NGATE5 5120
#define TSTEPS 8192
#define NWGC   128    // compute WGs (each owns 8 columns)
#define NWGR   8      // relay candidate WGs
#define NTHR   512

// workspace layout (u64 units unless noted)
#define HSLOT_OFF 0          // 1024 u64  (LLC slots, contiguous - R8 striding hurt)
#define VSLOT_OFF 1024       // 1024 u64
#define HMBOX_OFF 2048       // 8*1024 u64 per-XCD mailboxes
#define VMBOX_OFF 10240      // 8*1024 u64
#define CTRL_U64S 18432      // = 147456 bytes
#define XPROJ_BYTE_OFF 151552

typedef unsigned int u32x4 __attribute__((ext_vector_type(4)));

__device__ __forceinline__ float sigmoidf_(float x) {
  return 1.f / (1.f + __expf(-x));
}
__device__ __forceinline__ float tanhf_(float x) {
  float ax = fminf(fabsf(x), 15.f);
  float e = __expf(2.f * ax);
  float t = 1.f - 2.f / (e + 1.f);
  return copysignf(t, x);
}

// 16-B LLC-coherent load (bypass L1+L2; cross-XCD visible).
__device__ __forceinline__ u32x4 load16_llc(const unsigned long long* p) {
  u32x4 r;
  asm volatile("global_load_dwordx4 %0, %1, off sc0 sc1\n\t"
               "s_waitcnt vmcnt(0)"
               : "=&v"(r) : "v"(p) : "memory");
  return r;
}
// 16-B L2-coherent load (bypass L1 only; sees same-XCD stores).
__device__ __forceinline__ u32x4 load16_l2(const unsigned long long* p) {
  u32x4 r;
  asm volatile("global_load_dwordx4 %0, %1, off sc0\n\t"
               "s_waitcnt vmcnt(0)"
               : "=&v"(r) : "v"(p) : "memory");
  return r;
}

__device__ __forceinline__ unsigned long long pack_slot(float v, unsigned tag) {
  return ((unsigned long long)tag << 32) | (unsigned long long)__float_as_uint(v);
}
__device__ __forceinline__ unsigned long long pack_u(unsigned lo, unsigned hi) {
  return ((unsigned long long)hi << 32) | (unsigned long long)lo;
}
__device__ __forceinline__ void store_l2(unsigned long long* p, unsigned long long v) {
  __hip_atomic_store(p, v, __ATOMIC_RELAXED, __HIP_MEMORY_SCOPE_WORKGROUP); // plain -> own L2
}
__device__ __forceinline__ unsigned read_xcc() {
  unsigned x;
  asm volatile("s_getreg_b32 %0, hwreg(HW_REG_XCC_ID)" : "=s"(x));
  return x & 7u;
}

// Consumer poll: mailbox (L2, cheap) every round; LLC every 4th round as
// liveness fallback (+opportunistic republish). Stages 2 fp32 into dst.
__device__ __forceinline__ void poll_consume(
    const unsigned long long* __restrict__ llc,
    unsigned long long* __restrict__ mbx,
    float* __restrict__ dst, int sb, unsigned want, int phase)
{
  int r = phase;
  u32x4 a;
  for (;;) {
    a = load16_l2(mbx + sb);
    if (a.y == want && a.w == want) break;
    if ((r & 3) == 0) {
      u32x4 b = load16_llc(llc + sb);
      const bool lo = (b.y == want), hi = (b.w == want);
      if (lo) store_l2(mbx + sb,     pack_u(b.x, b.y));
      if (hi) store_l2(mbx + sb + 1, pack_u(b.z, b.w));
      if (lo && hi) { a = b; break; }
    }
    ++r;
  }
  dst[sb + 0] = __uint_as_float(a.x);
  dst[sb + 1] = __uint_as_float(a.z);
}

// Relay pump: poll 2 LLC atoms until fresh, republish each into mailbox once.
__device__ __forceinline__ void relay_pump(
    const unsigned long long* __restrict__ llc,
    unsigned long long* __restrict__ mbx, int sb, unsigned want)
{
  bool lo = false, hi = false;
  for (;;) {
    u32x4 b = load16_llc(llc + sb);
    if (!lo && b.y == want) { store_l2(mbx + sb,     pack_u(b.x, b.y)); lo = true; }
    if (!hi && b.w == want) { store_l2(mbx + sb + 1, pack_u(b.z, b.w)); hi = true; }
    if (lo && hi) return;
  }
}

// ---------------------------------------------------------------------------
// Prepass: xproj[t][r] = inputs[t,:]@Wx[r,:] + bx[r] + (r<4M ? bh[r] : bm[r-4M])
// ---------------------------------------------------------------------------
#define GT_K 16
__global__ __launch_bounds__(256) void xproj_gemm(
    const float* __restrict__ A, const float* __restrict__ W,
    const float* __restrict__ bx, const float* __restrict__ bh,
    const float* __restrict__ bm, float* __restrict__ C)
{
  __shared__ float As[GT_K][64 + 4];
  __shared__ float Ws[GT_K][64 + 4];
  const int tid = threadIdx.x;
  const int tx = tid & 15, ty = tid >> 4;
  const int m0 = blockIdx.x * 64;
  const int n0 = blockIdx.y * 64;
  const int lr = tid >> 2;
  const int lk = (tid & 3) * 4;

  float acc[4][4] = {};
  for (int kb = 0; kb < MDIM; kb += GT_K) {
    const float4 av = *(const float4*)(A + (size_t)(m0 + lr) * MDIM + kb + lk);
    const float4 wv = *(const float4*)(W + (size_t)(n0 + lr) * MDIM + kb + lk);
    __syncthreads();
    As[lk + 0][lr] = av.x; As[lk + 1][lr] = av.y;
    As[lk + 2][lr] = av.z; As[lk + 3][lr] = av.w;
    Ws[lk + 0][lr] = wv.x; Ws[lk + 1][lr] = wv.y;
    Ws[lk + 2][lr] = wv.z; Ws[lk + 3][lr] = wv.w;
    __syncthreads();
    #pragma unroll
    for (int kk = 0; kk < GT_K; ++kk) {
      const float4 a = *(const float4*)(&As[kk][ty * 4]);
      const float4 w = *(const float4*)(&Ws[kk][tx * 4]);
      acc[0][0] += a.x * w.x; acc[0][1] += a.x * w.y; acc[0][2] += a.x * w.z; acc[0][3] += a.x * w.w;
      acc[1][0] += a.y * w.x; acc[1][1] += a.y * w.y; acc[1][2] += a.y * w.z; acc[1][3] += a.y * w.w;
      acc[2][0] += a.z * w.x; acc[2][1] += a.z * w.y; acc[2][2] += a.z * w.z; acc[2][3] += a.z * w.w;
      acc[3][0] += a.w * w.x; acc[3][1] += a.w * w.y; acc[3][2] += a.w * w.z; acc[3][3] += a.w * w.w;
    }
  }
  const int rbase = n0 + tx * 4;
  float bias[4];
  #pragma unroll
  for (int q = 0; q < 4; ++q) {
    const int r = rbase + q;
    bias[q] = bx[r] + (r < 4 * MDIM ? bh[r] : bm[r - 4 * MDIM]);
  }
  #pragma unroll
  for (int i = 0; i < 4; ++i) {
    const int row = m0 + ty * 4 + i;
    float4 o;
    o.x = acc[i][0] + bias[0]; o.y = acc[i][1] + bias[1];
    o.z = acc[i][2] + bias[2]; o.w = acc[i][3] + bias[3];
    *(float4*)(C + (size_t)row * NGATE5 + rbase) = o;
  }
}

// ---------------------------------------------------------------------------
// Persistent kernel: blockIdx<128 = compute (R6 structure: Wh in LDS 128 KB,
// Wm in regs, z-first overlap); blockIdx>=128 = relay candidates (one claims
// each XCD via XCC_ID + CAS, pumps LLC->L2 mailbox).
// ---------------------------------------------------------------------------
__global__ __launch_bounds__(NTHR, 2) void ulstm_persistent_p(
    const float* __restrict__ Wh, const float* __restrict__ Wm,
    const float* __restrict__ xproj, float* __restrict__ out,
    unsigned long long* __restrict__ ws, int* __restrict__ claim)
{
  __shared__ alignas(16) float sWh[32][MDIM];   // 128 KB
  __shared__ alignas(16) float hbuf[MDIM];
  __shared__ alignas(16) float vbuf[MDIM];

  unsigned long long* __restrict__ hslot = ws + HSLOT_OFF;
  unsigned long long* __restrict__ vslot = ws + VSLOT_OFF;
  const unsigned xcc = read_xcc();
  unsigned long long* __restrict__ hmbox = ws + HMBOX_OFF + (size_t)xcc * MDIM;
  unsigned long long* __restrict__ vmbox = ws + VMBOX_OFF + (size_t)xcc * MDIM;

  const int tid = threadIdx.x;
  const int sb  = tid * 2;

  // ---------------- relay path ----------------
  if (blockIdx.x >= NWGC) {
    __shared__ int win;
    if (tid == 0) win = (atomicCAS(claim + xcc, 0, 1) == 0) ? 1 : 0;
    __syncthreads();
    if (!win) return;
    for (int t = 0; t < TSTEPS; ++t) {
      relay_pump(hslot, hmbox, sb, (unsigned)t);
      relay_pump(vslot, vmbox, sb, (unsigned)(t + 1));
    }
    return;
  }

  // ---------------- compute path ----------------
  const int wg   = blockIdx.x;
  const int wave = tid >> 6;
  const int lane = tid & 63;
  const int j    = wg * 8 + wave;          // owned column
  const int phase = wg & 3;

  for (int idx = tid; idx < 32 * 256; idx += NTHR) {
    const int r = idx >> 8, k4 = (idx & 255) * 4;
    const int w_ = r >> 2, g = r & 3;
    *(float4*)(&sWh[r][k4]) =
        *(const float4*)(Wh + (size_t)(g * MDIM + wg * 8 + w_) * MDIM + k4);
  }
  float wm[16];
  #pragma unroll
  for (int i = 0; i < 4; ++i) {
    const float4 v = *(const float4*)(Wm + (size_t)j * MDIM + i * 256 + lane * 4);
    wm[i * 4 + 0] = v.x; wm[i * 4 + 1] = v.y;
    wm[i * 4 + 2] = v.z; wm[i * 4 + 3] = v.w;
  }
  __syncthreads();

  float c = 0.f, hlast = 0.f, tc = 0.f;

  for (int t = 0; t < TSTEPS; ++t) {
    const float* xp = xproj + (size_t)t * NGATE5 + j;
    const float xw0 = xp[0 * MDIM];
    const float xw1 = xp[1 * MDIM];
    const float xw2 = xp[2 * MDIM];
    const float xw3 = xp[3 * MDIM];
    const float xw4 = xp[4 * MDIM];

    // ---- wait for h(t-1): tag==t ----
    poll_consume(hslot, hmbox, hbuf, sb, (unsigned)t, phase);
    __syncthreads();

    // ---- z-dot (critical path), publish v ----
    float hd2 = 0.f;
    #pragma unroll
    for (int i = 0; i < 4; ++i) {
      const int kb = i * 256 + lane * 4;
      const float4 hv = *(const float4*)(hbuf + kb);
      const float4 w2 = *(const float4*)(&sWh[wave * 4 + 2][kb]);
      hd2 += w2.x * hv.x + w2.y * hv.y + w2.z * hv.z + w2.w * hv.w;
    }
    #pragma unroll
    for (int off = 32; off > 0; off >>= 1) hd2 += __shfl_xor(hd2, off, 64);

    const float zg = sigmoidf_(xw2 + hd2);
    const float vj = zg * tc;
    if (lane == 0) {
      const unsigned long long atom = pack_slot(vj, (unsigned)(t + 1));
      __hip_atomic_store(vslot + j, atom, __ATOMIC_RELAXED, __HIP_MEMORY_SCOPE_AGENT);
      store_l2(vmbox + j, atom);   // same-XCD fast path
    }

    // ---- i,o,f dots overlap the v-exchange ----
    float hd0 = 0.f, hd1 = 0.f, hd3 = 0.f;
    #pragma unroll
    for (int i = 0; i < 4; ++i) {
      const int kb = i * 256 + lane * 4;
      const float4 hv = *(const float4*)(hbuf + kb);
      const float4 w0 = *(const float4*)(&sWh[wave * 4 + 0][kb]);
      const float4 w1 = *(const float4*)(&sWh[wave * 4 + 1][kb]);
      const float4 w3 = *(const float4*)(&sWh[wave * 4 + 3][kb]);
      hd0 += w0.x * hv.x + w0.y * hv.y + w0.z * hv.z + w0.w * hv.w;
      hd1 += w1.x * hv.x + w1.y * hv.y + w1.z * hv.z + w1.w * hv.w;
      hd3 += w3.x * hv.x + w3.y * hv.y + w3.z * hv.z + w3.w * hv.w;
    }
    #pragma unroll
    for (int off = 32; off > 0; off >>= 1) {
      hd0 += __shfl_xor(hd0, off, 64);
      hd1 += __shfl_xor(hd1, off, 64);
      hd3 += __shfl_xor(hd3, off, 64);
    }
    const float ig = sigmoidf_(xw0 + hd0);
    const float og = sigmoidf_(xw1 + hd1);
    const float fg = sigmoidf_(xw3 + hd3);

    // ---- wait for v(t): tag==t+1 ----
    poll_consume(vslot, vmbox, vbuf, sb, (unsigned)(t + 1), phase);
    __syncthreads();

    // ---- u-dot from registers ----
    float md = 0.f;
    #pragma unroll
    for (int i = 0; i < 4; ++i) {
      const int kb = i * 256 + lane * 4;
      const float4 vv = *(const float4*)(vbuf + kb);
      md += wm[i*4+0]*vv.x + wm[i*4+1]*vv.y + wm[i*4+2]*vv.z + wm[i*4+3]*vv.w;
    }
    #pragma unroll
    for (int off = 32; off > 0; off >>= 1) md += __shfl_xor(md, off, 64);

    const float u = tanhf_(xw4 + md);
    c = ig * u + fg * c;
    const float tcn = tanhf_(c);
    hlast = og * tcn;
    if (lane == 0) {
      const unsigned long long atom = pack_slot(hlast, (unsigned)(t + 1));
      __hip_atomic_store(hslot + j, atom, __ATOMIC_RELAXED, __HIP_MEMORY_SCOPE_AGENT);
      store_l2(hmbox + j, atom);
    }
    tc = tcn;
  }

  if (lane == 0) {
    out[j] = c;
    out[MDIM + j] = hlast;
  }
}

// ---------------------------------------------------------------------------
// Fallback (ws too small for xproj): R6-style, LLC-only serial polls.
// ---------------------------------------------------------------------------
__global__ __launch_bounds__(256, 1) void ulstm_persistent_f(
    const float* __restrict__ inputs, const float* __restrict__ Wx,
    const float* __restrict__ bx, const float* __restrict__ Wh,
    const float* __restrict__ bh, const float* __restrict__ Wm,
    const float* __restrict__ bm, float* __restrict__ out,
    unsigned long long* __restrict__ hslot, unsigned long long* __restrict__ vslot)
{
  __shared__ alignas(16) float xbuf[MDIM];
  __shared__ alignas(16) float hbuf[MDIM];
  __shared__ alignas(16) float vbuf[MDIM];

  const int tid  = threadIdx.x;
  const int wg   = blockIdx.x;
  const int wave = tid >> 6;
  const int lane = tid & 63;
  const int j    = wg * 4 + wave;
  const int sb   = tid * 4;

  const float bxi = bx[j],            bxo = bx[MDIM + j],
              bxz = bx[2 * MDIM + j], bxf = bx[3 * MDIM + j],
              bxu = bx[4 * MDIM + j];
  const float bhi = bh[j],            bho = bh[MDIM + j],
              bhz = bh[2 * MDIM + j], bhf = bh[3 * MDIM + j];
  const float bmj = bm[j];

  float c = 0.f, hlast = 0.f;

  for (int t = 0; t < TSTEPS; ++t) {
    {
      float4 v = ((const float4*)(inputs + (size_t)t * MDIM))[tid];
      ((float4*)xbuf)[tid] = v;
    }
    __syncthreads();

    float xd[5] = {0, 0, 0, 0, 0};
    #pragma unroll
    for (int i = 0; i < 4; ++i) {
      const int kb = i * 256 + lane * 4;
      const float4 xv = *(const float4*)(xbuf + kb);
      #pragma unroll
      for (int g = 0; g < 5; ++g) {
        const float4 w = *(const float4*)(Wx + ((size_t)(g * MDIM + j)) * MDIM + kb);
        xd[g] += w.x * xv.x + w.y * xv.y + w.z * xv.z + w.w * xv.w;
      }
    }
    #pragma unroll
    for (int off = 32; off > 0; off >>= 1)
      #pragma unroll
      for (int g = 0; g < 5; ++g) xd[g] += __shfl_xor(xd[g], off, 64);

    {
      u32x4 a, b;
      for (;;) {
        a = load16_llc(hslot + sb);
        b = load16_llc(hslot + sb + 2);
        if (a.y == (unsigned)t && a.w == (unsigned)t &&
            b.y == (unsigned)t && b.w == (unsigned)t) break;
      }
      hbuf[sb + 0] = __uint_as_float(a.x);
      hbuf[sb + 1] = __uint_as_float(a.z);
      hbuf[sb + 2] = __uint_as_float(b.x);
      hbuf[sb + 3] = __uint_as_float(b.z);
    }
    __syncthreads();

    float hd[4] = {0, 0, 0, 0};
    #pragma unroll
    for (int i = 0; i < 4; ++i) {
      const int kb = i * 256 + lane * 4;
      const float4 hv = *(const float4*)(hbuf + kb);
      #pragma unroll
      for (int g = 0; g < 4; ++g) {
        const float4 w = *(const float4*)(Wh + ((size_t)(g * MDIM + j)) * MDIM + kb);
        hd[g] += w.x * hv.x + w.y * hv.y + w.z * hv.z + w.w * hv.w;
      }
    }
    #pragma unroll
    for (int off = 32; off > 0; off >>= 1)
      #pragma unroll
      for (int g = 0; g < 4; ++g) hd[g] += __shfl_xor(hd[g], off, 64);

    const float ig = sigmoidf_(xd[0] + bxi + hd[0] + bhi);
    const float og = sigmoidf_(xd[1] + bxo + hd[1] + bho);
    const float zg = sigmoidf_(xd[2] + bxz + hd[2] + bhz);
    const float fg = sigmoidf_(xd[3] + bxf + hd[3] + bhf);
    const float vj = zg * tanhf_(c);
    if (lane == 0)
      __hip_atomic_store(vslot + j, pack_slot(vj, (unsigned)(t + 1)),
                         __ATOMIC_RELAXED, __HIP_MEMORY_SCOPE_AGENT);

    {
      u32x4 a, b;
      for (;;) {
        a = load16_llc(vslot + sb);
        b = load16_llc(vslot + sb + 2);
        if (a.y == (unsigned)(t + 1) && a.w == (unsigned)(t + 1) &&
            b.y == (unsigned)(t + 1) && b.w == (unsigned)(t + 1)) break;
      }
      vbuf[sb + 0] = __uint_as_float(a.x);
      vbuf[sb + 1] = __uint_as_float(a.z);
      vbuf[sb + 2] = __uint_as_float(b.x);
      vbuf[sb + 3] = __uint_as_float(b.z);
    }
    __syncthreads();

    float md = 0;
    #pragma unroll
    for (int i = 0; i < 4; ++i) {
      const int kb = i * 256 + lane * 4;
      const float4 vv = *(const float4*)(vbuf + kb);
      const float4 w = *(const float4*)(Wm + (size_t)j * MDIM + kb);
      md += w.x * vv.x + w.y * vv.y + w.z * vv.z + w.w * vv.w;
    }
    #pragma unroll
    for (int off = 32; off > 0; off >>= 1) md += __shfl_xor(md, off, 64);

    const float u = tanhf_(xd[4] + bxu + md + bmj);
    c = ig * u + fg * c;
    hlast = og * tanhf_(c);
    if (lane == 0)
      __hip_atomic_store(hslot + j, pack_slot(hlast, (unsigned)(t + 1)),
                         __ATOMIC_RELAXED, __HIP_MEMORY_SCOPE_AGENT);
  }

  if (lane == 0) {
    out[j] = c;
    out[MDIM + j] = hlast;
  }
}

extern "C" void kernel_launch(void* const* d_in, const int* in_sizes, int n_in,
                              void* d_out, int out_size, void* d_ws, size_t ws_size,
                              hipStream_t stream) {
  const float* inputs = (const float*)d_in[0];
  const float* Wx     = (const float*)d_in[1];
  const float* bx     = (const float*)d_in[2];
  const float* Wh     = (const float*)d_in[3];
  const float* bh     = (const float*)d_in[4];
  const float* Wm     = (const float*)d_in[5];
  const float* bm     = (const float*)d_in[6];
  float* out = (float*)d_out;

  unsigned long long* ws64 = (unsigned long long*)d_ws;
  int* claim = (int*)((char*)d_ws + CTRL_U64S * sizeof(unsigned long long));
  const size_t ctrl_bytes = XPROJ_BYTE_OFF;   // slots + mailboxes + claim (+pad)
  const size_t xp_bytes   = (size_t)TSTEPS * NGATE5 * sizeof(float);

  if (ws_size >= ctrl_bytes + xp_bytes) {
    // tag 0 / value 0.0f everywhere == initial h state; claim[]=0
    hipMemsetAsync(d_ws, 0, ctrl_bytes, stream);
    float* xproj = (float*)((char*)d_ws + XPROJ_BYTE_OFF);
    xproj_gemm<<<dim3(TSTEPS / 64, NGATE5 / 64), 256, 0, stream>>>(
        inputs, Wx, bx, bh, bm, xproj);
    ulstm_persistent_p<<<NWGC + NWGR, NTHR, 0, stream>>>(
        Wh, Wm, xproj, out, ws64, claim);
  } else {
    hipMemsetAsync(d_ws, 0, 2 * MDIM * sizeof(unsigned long long), stream);
    ulstm_persistent_f<<<256, 256, 0, stream>>>(inputs, Wx, bx, Wh, bh, Wm, bm,
                                                out, ws64 + HSLOT_OFF, ws64 + VSLOT_OFF);
  }
}